// Round 3
// baseline (57.255 us; speedup 1.0000x reference)
//
#include <hip/hip_runtime.h>

// out[b,c,di,dj] = (1/L) * clamped_boxsum_31x31(x)[di,dj] - center_patch
//   (ci,cj) = divmod(center_idx, 31); center_patch = shifted x with zero pad.
// One block (256 thr = 4 waves) per (b,c) image; separable box-sum via
// row/col prefix sums in LDS. Flat LDS (stride 31, odd) -> conflict-free
// both for row walks (stride 1) and column walks (stride 31 ≡ all banks).

#define KS 31
#define PAD 15
#define LL 961  // KS*KS

__global__ __launch_bounds__(256) void
IrregularDirectionalGradientConv_34144990003267_kernel(const float* __restrict__ x,
                                                       const int* __restrict__ cidx,
                                                       float* __restrict__ out) {
    __shared__ float xs[LL];              // image, flat [31][31]
    __shared__ float rp[KS][KS + 2];      // row prefix sums, rp[r][j+1] = sum x[r][0..j]
    __shared__ float rs[LL];              // clamped row window sums, flat
    __shared__ float cp[KS + 2][KS + 1];  // column prefix of rs

    const int bc = blockIdx.x;  // 0..255 = b*32 + c
    const float* __restrict__ img = x + (size_t)bc * LL;
    float* __restrict__ o = out + (size_t)bc * LL;
    const int tid = threadIdx.x;

    // Issue the scalar center-index load early; latency hides under staging.
    const int center = cidx[0];

    #pragma unroll
    for (int i = tid; i < LL; i += 256) xs[i] = img[i];
    __syncthreads();

    // Row prefix sums: threads 0..30, one per row (31 independent ds_reads,
    // then a 31-add chain — a few hundred cycles total).
    if (tid < KS) {
        float s = 0.f;
        rp[tid][0] = 0.f;
        #pragma unroll
        for (int j = 0; j < KS; ++j) { s += xs[tid * KS + j]; rp[tid][j + 1] = s; }
    }
    __syncthreads();

    // Clamped horizontal window sum per element (4 elems/thread).
    #pragma unroll
    for (int i = tid; i < LL; i += 256) {
        int r = i / KS, c = i - r * KS;
        int lo = c - PAD; if (lo < 0) lo = 0;
        int hi = c + PAD; if (hi > KS - 1) hi = KS - 1;
        rs[i] = rp[r][hi + 1] - rp[r][lo];
    }
    __syncthreads();

    // Column prefix sums: threads 0..30, one per column. Reads rs[i*31+tid]:
    // lanes 0..30 hit consecutive banks each iteration — conflict-free.
    if (tid < KS) {
        float s = 0.f;
        cp[0][tid] = 0.f;
        #pragma unroll
        for (int i = 0; i < KS; ++i) { s += rs[i * KS + tid]; cp[i + 1][tid] = s; }
    }
    __syncthreads();

    const int ci = center / KS;
    const int cj = center - ci * KS;
    #pragma unroll
    for (int i = tid; i < LL; i += 256) {
        int r = i / KS, c = i - r * KS;
        int lo = r - PAD; if (lo < 0) lo = 0;
        int hi = r + PAD; if (hi > KS - 1) hi = KS - 1;
        float ws = cp[hi + 1][c] - cp[lo][c];

        int rr = ci + r - PAD;
        int cc = cj + c - PAD;
        float cen = (rr >= 0 && rr < KS && cc >= 0 && cc < KS) ? xs[rr * KS + cc] : 0.f;

        o[i] = ws * (1.0f / (float)LL) - cen;
    }
}

extern "C" void kernel_launch(void* const* d_in, const int* in_sizes, int n_in,
                              void* d_out, int out_size, void* d_ws, size_t ws_size,
                              hipStream_t stream) {
    const float* x = (const float*)d_in[0];
    const int* cidx = (const int*)d_in[1];
    float* out = (float*)d_out;
    // B*C = 8*32 = 256 images of 31x31 — one block per image, one per CU.
    IrregularDirectionalGradientConv_34144990003267_kernel<<<256, 256, 0, stream>>>(x, cidx, out);
}